// Round 4
// baseline (169.372 us; speedup 1.0000x reference)
//
#include <hip/hip_runtime.h>
#include <math.h>

// Model collapses (softmax over a length-1 key axis == 1.0 => ctx == V) to a
// per-row MLP on biobert_cls [256,768]:
//   V      = bio @ ca_wv + ca_bv                 [256,256]
//   ctx    = LN(V @ ca_wo + ca_bo; ca_ln)
//   ffn    = relu(ctx @ w1 + b1) @ w2 + b2
//   outr   = LN(ctx + ffn; fn)
//   logits = outr @ fc_w + fc_b                  [256,5]
//
// R4: weight traffic was the limiter (402 MB through L2 at ~13 TB/s eff).
//  - 64 blocks x 4 rows/block: one weight fetch -> 16 FMAs (4 rows x 4 ch)
//  - weights pre-packed to bf16 in d_ws by cvt_weights (runs every launch,
//    same work every call): bytes 402 -> 50 MB total.
// Activations, stats, accumulation all stay fp32.

#define WV_ELEMS  (768 * 256)
#define W256_ELEMS (256 * 256)

__device__ __forceinline__ unsigned short f2bf_rne(float x) {
    unsigned u = __float_as_uint(x);
    unsigned r = (u + 0x7fffu + ((u >> 16) & 1u)) >> 16;   // round-nearest-even
    return (unsigned short)r;
}
__device__ __forceinline__ float bf_lo(unsigned u) { return __uint_as_float(u << 16); }
__device__ __forceinline__ float bf_hi(unsigned u) { return __uint_as_float(u & 0xffff0000u); }

// Pack wv(768x256), wo, w1, w2 (256x256 each) into bf16 at d_ws.
// 98304 float4 slots total = 384 blocks x 256 threads.
__global__ __launch_bounds__(256)
void cvt_weights(const float* __restrict__ wv, const float* __restrict__ wo,
                 const float* __restrict__ w1, const float* __restrict__ w2,
                 unsigned short* __restrict__ dst) {
    int i = blockIdx.x * 256 + threadIdx.x;    // float4 slot
    const float4* src; int li;
    if (i < 49152)      { src = (const float4*)wv; li = i; }
    else if (i < 65536) { src = (const float4*)wo; li = i - 49152; }
    else if (i < 81920) { src = (const float4*)w1; li = i - 65536; }
    else                { src = (const float4*)w2; li = i - 81920; }
    float4 v = src[li];
    ushort4 o;
    o.x = f2bf_rne(v.x); o.y = f2bf_rne(v.y); o.z = f2bf_rne(v.z); o.w = f2bf_rne(v.w);
    ((ushort4*)dst)[i] = o;
}

// LN stats for 4 rows. Thread tid holds x0 for (r0=tid>>8, c=tid&255) and
// x1 for (r0+2, c). All 512 threads call (uniform barriers).
__device__ __forceinline__ void ln_stats4(float x0, float x1, int tid,
        float (*ssum)[4], float (*ssq)[4], float (*stats)[2],
        float& m0, float& rs0, float& m1, float& rs1)
{
    float s0 = x0, q0 = x0 * x0, s1 = x1, q1 = x1 * x1;
    #pragma unroll
    for (int o = 32; o > 0; o >>= 1) {
        s0 += __shfl_down(s0, o); q0 += __shfl_down(q0, o);
        s1 += __shfl_down(s1, o); q1 += __shfl_down(q1, o);
    }
    const int lane = tid & 63;
    if (lane == 0) {
        int r0 = tid >> 8, w = (tid >> 6) & 3;   // 4 waves per row
        ssum[r0][w] = s0;     ssq[r0][w] = q0;
        ssum[r0 + 2][w] = s1; ssq[r0 + 2][w] = q1;
    }
    __syncthreads();
    if (tid < 4) {
        float S = ssum[tid][0] + ssum[tid][1] + ssum[tid][2] + ssum[tid][3];
        float Q = ssq[tid][0] + ssq[tid][1] + ssq[tid][2] + ssq[tid][3];
        float mm  = S * (1.0f / 256.0f);
        float var = Q * (1.0f / 256.0f) - mm * mm;   // biased var (jnp.var)
        stats[tid][0] = mm;
        stats[tid][1] = rsqrtf(fmaxf(var, 0.0f) + 1e-5f);
    }
    __syncthreads();
    int r0 = tid >> 8;
    m0 = stats[r0][0];     rs0 = stats[r0][1];
    m1 = stats[r0 + 2][0]; rs1 = stats[r0 + 2][1];
    __syncthreads();                                  // protect before reuse
}

__global__ __launch_bounds__(512)
void mlp_head_kernel(const float* __restrict__ bio,          // [256,768]
                     const unsigned short* __restrict__ wpack,
                     const float* __restrict__ bv, const float* __restrict__ bo,
                     const float* __restrict__ lng, const float* __restrict__ lnb,
                     const float* __restrict__ b1, const float* __restrict__ b2,
                     const float* __restrict__ fng, const float* __restrict__ fnb,
                     const float* __restrict__ fcw, const float* __restrict__ fcb,
                     float* __restrict__ out)                // [256,5]
{
    const int b   = blockIdx.x;     // rows 4b..4b+3
    const int tid = threadIdx.x;
    const int q   = tid >> 6;       // K-group 0..7
    const int co  = tid & 63;       // channel quad: 4co..4co+3

    const unsigned short* wv16 = wpack;
    const unsigned short* wo16 = wpack + WV_ELEMS;
    const unsigned short* w116 = wo16 + W256_ELEMS;
    const unsigned short* w216 = w116 + W256_ELEMS;

    __shared__ float s_bio[4][768];
    __shared__ float s_act[4][256];
    __shared__ float s_part[8][4][256];
    __shared__ float s_sum[4][4], s_sq[4][4], s_stats[4][2];

    for (int i = tid; i < 4 * 768; i += 512)
        ((float*)s_bio)[i] = bio[b * 3072 + i];
    __syncthreads();

    // GEMM partial: weights bf16 [k][256]; this thread: K rows q*KG..q*KG+KG-1,
    // channels 4co..4co+3, all 4 activation rows. Trailing sync included.
    #define GEMM_BF16(W16, KG, SRC, SSTR) {                                   \
        float4 a0 = {0,0,0,0}, a1 = {0,0,0,0}, a2 = {0,0,0,0}, a3 = {0,0,0,0};\
        const uint2* wp = (const uint2*)(W16) + (q * (KG)) * 64 + co;         \
        const float* x0 = (SRC) + 0 * (SSTR) + q * (KG);                      \
        const float* x1 = (SRC) + 1 * (SSTR) + q * (KG);                      \
        const float* x2 = (SRC) + 2 * (SSTR) + q * (KG);                      \
        const float* x3 = (SRC) + 3 * (SSTR) + q * (KG);                      \
        _Pragma("unroll 8")                                                   \
        for (int k = 0; k < (KG); ++k) {                                      \
            uint2 u = wp[k * 64];                                             \
            float wa = bf_lo(u.x), wb = bf_hi(u.x);                           \
            float wc = bf_lo(u.y), wd = bf_hi(u.y);                           \
            float v0 = x0[k], v1 = x1[k], v2 = x2[k], v3 = x3[k];             \
            a0.x = fmaf(v0, wa, a0.x); a0.y = fmaf(v0, wb, a0.y);             \
            a0.z = fmaf(v0, wc, a0.z); a0.w = fmaf(v0, wd, a0.w);             \
            a1.x = fmaf(v1, wa, a1.x); a1.y = fmaf(v1, wb, a1.y);             \
            a1.z = fmaf(v1, wc, a1.z); a1.w = fmaf(v1, wd, a1.w);             \
            a2.x = fmaf(v2, wa, a2.x); a2.y = fmaf(v2, wb, a2.y);             \
            a2.z = fmaf(v2, wc, a2.z); a2.w = fmaf(v2, wd, a2.w);             \
            a3.x = fmaf(v3, wa, a3.x); a3.y = fmaf(v3, wb, a3.y);             \
            a3.z = fmaf(v3, wc, a3.z); a3.w = fmaf(v3, wd, a3.w);             \
        }                                                                     \
        ((float4*)s_part[q][0])[co] = a0;                                     \
        ((float4*)s_part[q][1])[co] = a1;                                     \
        ((float4*)s_part[q][2])[co] = a2;                                     \
        ((float4*)s_part[q][3])[co] = a3;                                     \
    }                                                                         \
    __syncthreads();

    // Thread tid reduces outputs (r0, c) and (r0+2, c).
    #define REDUCE2(V0, V1) {                                                 \
        const int rr = tid >> 8, cc = tid & 255;                              \
        float p0_ = 0.f, p1_ = 0.f;                                           \
        _Pragma("unroll")                                                     \
        for (int g = 0; g < 8; ++g) {                                         \
            p0_ += s_part[g][rr][cc]; p1_ += s_part[g][rr + 2][cc];           \
        }                                                                     \
        V0 = p0_; V1 = p1_;                                                   \
    }

    // ---- V = bio @ wv + bv ----
    GEMM_BF16(wv16, 96, (const float*)s_bio, 768);
    {
        float p0, p1; REDUCE2(p0, p1);
        const int rr = tid >> 8, cc = tid & 255;
        float bb = bv[cc];
        s_act[rr][cc] = p0 + bb;
        s_act[rr + 2][cc] = p1 + bb;
    }
    __syncthreads();

    // ---- t = V @ wo + bo ; ctx = LN(t) ----
    float ctx0, ctx1;
    GEMM_BF16(wo16, 32, (const float*)s_act, 256);
    {
        float p0, p1; REDUCE2(p0, p1);
        const int rr = tid >> 8, cc = tid & 255;
        float bb = bo[cc];
        float t0 = p0 + bb, t1 = p1 + bb;
        float m0, rs0, m1, rs1;
        ln_stats4(t0, t1, tid, s_sum, s_sq, s_stats, m0, rs0, m1, rs1);
        float g = lng[cc], be = lnb[cc];
        ctx0 = (t0 - m0) * rs0 * g + be;
        ctx1 = (t1 - m1) * rs1 * g + be;
        s_act[rr][cc] = ctx0;
        s_act[rr + 2][cc] = ctx1;
    }
    __syncthreads();

    // ---- u = relu(ctx @ w1 + b1) ----
    GEMM_BF16(w116, 32, (const float*)s_act, 256);
    {
        float p0, p1; REDUCE2(p0, p1);
        const int rr = tid >> 8, cc = tid & 255;
        float bb = b1[cc];
        s_act[rr][cc] = fmaxf(p0 + bb, 0.0f);
        s_act[rr + 2][cc] = fmaxf(p1 + bb, 0.0f);
    }
    __syncthreads();

    // ---- f = u @ w2 + b2 ; outr = LN(ctx + f) ----
    GEMM_BF16(w216, 32, (const float*)s_act, 256);
    {
        float p0, p1; REDUCE2(p0, p1);
        const int rr = tid >> 8, cc = tid & 255;
        float bb = b2[cc];
        float o0 = p0 + bb + ctx0, o1 = p1 + bb + ctx1;
        float m0, rs0, m1, rs1;
        ln_stats4(o0, o1, tid, s_sum, s_sq, s_stats, m0, rs0, m1, rs1);
        float g = fng[cc], be = fnb[cc];
        s_act[rr][cc] = (o0 - m0) * rs0 * g + be;
        s_act[rr + 2][cc] = (o1 - m1) * rs1 * g + be;
    }
    __syncthreads();

    // ---- logits = outr @ fc_w + fc_b  (fc_w is [256,5]) ----
    // wave w<4 handles row w; lane l sums k = l, l+64, l+128, l+192.
    if (q < 4) {
        const int lane = tid & 63;
        float acc[5] = {0, 0, 0, 0, 0};
        #pragma unroll
        for (int e = 0; e < 4; ++e) {
            int k = lane + 64 * e;
            float xv = s_act[q][k];
            #pragma unroll
            for (int c = 0; c < 5; ++c) acc[c] = fmaf(xv, fcw[k * 5 + c], acc[c]);
        }
        #pragma unroll
        for (int o2 = 32; o2 > 0; o2 >>= 1) {
            #pragma unroll
            for (int c = 0; c < 5; ++c) acc[c] += __shfl_down(acc[c], o2);
        }
        if (lane == 0) {
            #pragma unroll
            for (int c = 0; c < 5; ++c) out[(4 * b + q) * 5 + c] = acc[c] + fcb[c];
        }
    }
    #undef GEMM_BF16
    #undef REDUCE2
}

extern "C" void kernel_launch(void* const* d_in, const int* in_sizes, int n_in,
                              void* d_out, int out_size, void* d_ws, size_t ws_size,
                              hipStream_t stream) {
    // input order: 0:x 1:biobert_cls 2..25 gat/bn params (dead)
    // 26:ca_wq 27:ca_bq 28:ca_wk 29:ca_bk 30:ca_wv 31:ca_bv 32:ca_wo 33:ca_bo
    // 34:ca_ln_g 35:ca_ln_b 36:ffn_w1 37:ffn_b1 38:ffn_w2 39:ffn_b2
    // 40:fc_w 41:fc_b 42:fn_g 43:fn_b 44:edge_src 45:edge_dst 46:batch
    const float* bio = (const float*)d_in[1];
    const float* wv  = (const float*)d_in[30];
    const float* bv  = (const float*)d_in[31];
    const float* wo  = (const float*)d_in[32];
    const float* bo  = (const float*)d_in[33];
    const float* lng = (const float*)d_in[34];
    const float* lnb = (const float*)d_in[35];
    const float* w1  = (const float*)d_in[36];
    const float* b1  = (const float*)d_in[37];
    const float* w2  = (const float*)d_in[38];
    const float* b2  = (const float*)d_in[39];
    const float* fcw = (const float*)d_in[40];
    const float* fcb = (const float*)d_in[41];
    const float* fng = (const float*)d_in[42];
    const float* fnb = (const float*)d_in[43];
    float* out = (float*)d_out;
    unsigned short* wpack = (unsigned short*)d_ws;   // 786432 bf16 = 1.5 MB < ws

    hipLaunchKernelGGL(cvt_weights, dim3(384), dim3(256), 0, stream,
                       wv, wo, w1, w2, wpack);
    hipLaunchKernelGGL(mlp_head_kernel, dim3(64), dim3(512), 0, stream,
                       bio, wpack, bv, bo, lng, lnb, b1, b2,
                       fng, fnb, fcw, fcb, out);
}